// Round 4
// baseline (155.580 us; speedup 1.0000x reference)
//
#include <hip/hip_runtime.h>
#include <cstdint>

// DetNet NMS, round 22. r21 post-mortem: helper-gate split REGRESSED (k34
// 72us). Revised model from r19 occupancy: builders ~19us, then ~47us tail
// with ONLY block 0 resident -> tail is the consumer<->helper HANDSHAKE
// latency (res_prog -> helper sleep-spin -> done atomic -> h_prog -> ballot
// spin ~= 2-3.5K cyc/chunk x 32), not build-gating and not scan work (bit
// loop iterates once per KEPT box only; kept is small).
// r22: kill helpers + cascade. Consumer = ONE wave; dead state (128 u64)
// lives in per-lane REGISTERS (lane l owns words 2l,2l+1). Per kept row r:
// one coalesced 1KB load of mask[r] OR'd into the regs (covers all future
// chunks; replaces cascade + helpers). dlo/dhi = 2 readlanes from lane T.
// Kept outputs written immediately (lanes 0-4, 5 floats). Poison in words
// <2c of kept rows lands only in lanes owning past chunks (never re-read)
// -- same safety argument as r18 helpers. Builders: r19-proven chunk-major
// enumeration (doneD dropped). k2: r19 exact. Deadlock-free: consumer spins
// only on done[] exact-cover counters; builders never spin.
// All decision-critical FP math __f*_rn in exact ref op order (absmax 0.0
// r1-4, 6-9, 11-15, 17-21).

#define M_TOT 8192
#define NMS_T 0.3f

// ws layout (bytes)
#define WS_BOX   65536      // float4[8192]
#define WS_D     196608     // float[40960]
#define WS_VCNT  360448     // u32
#define WS_ZROW  393216     // u64[128] dummy zero row (zeroed by k2)
#define WS_DONE  458752     // u32[64] per-chunk full-strip counters (zeroed by k2)
#define WS_MASK  524288     // u64[8192*128] = 8 MB

typedef unsigned long long u64t;

__device__ __forceinline__ uint32_t desc_key(float sv) {
    uint32_t u = __float_as_uint(sv);
    uint32_t m = (u & 0x80000000u) ? ~u : (u | 0x80000000u);
    return ~m;
}
__device__ __forceinline__ u64t rdl64(u64t v, int sl) {
    unsigned lo = (unsigned)__builtin_amdgcn_readlane((int)(unsigned)v, sl);
    unsigned hi = (unsigned)__builtin_amdgcn_readlane((int)(unsigned)(v >> 32), sl);
    return ((u64t)hi << 32) | lo;
}

__device__ __forceinline__ void scatter_one(
    int i, int rank, u64t key,
    const float* __restrict__ det, const float* __restrict__ offsets,
    const float* __restrict__ scales,
    float4* __restrict__ boxes_srt, float* __restrict__ d_srt)
{
    uint32_t dkey = (uint32_t)(key >> 16);
    if (dkey >= 0x7FFFFFFFu) return;     // score <= 0: row stays zero
    int g = i >> 10;
    float d0 = __fadd_rn(offsets[g*5+0], __fmul_rn(det[i*5+0], scales[g*5+0]));
    float d1 = __fadd_rn(offsets[g*5+1], __fmul_rn(det[i*5+1], scales[g*5+1]));
    float d2 = __fadd_rn(offsets[g*5+2], __fmul_rn(det[i*5+2], scales[g*5+2]));
    float d3 = __fadd_rn(offsets[g*5+3], __fmul_rn(det[i*5+3], scales[g*5+3]));
    float d4 = __fadd_rn(offsets[g*5+4], __fmul_rn(det[i*5+4], scales[g*5+4]));
    d_srt[rank*5+0] = d0; d_srt[rank*5+1] = d1; d_srt[rank*5+2] = d2;
    d_srt[rank*5+3] = d3; d_srt[rank*5+4] = d4;
    float hw = __fmul_rn(d3, 0.5f), hh = __fmul_rn(d4, 0.5f);
    boxes_srt[rank] = make_float4(__fsub_rn(d1, hw), __fsub_rn(d2, hh),
                                  __fadd_rn(d1, hw), __fadd_rn(d2, hh));
}

// 128 blocks x 512 threads
__global__ __launch_bounds__(512) void k2_rank(
    const float* __restrict__ det, const float* __restrict__ offsets,
    const float* __restrict__ scales, const float* __restrict__ bounds,
    float4* __restrict__ boxes_srt, float* __restrict__ d_srt,
    unsigned int* __restrict__ vcnt, u64t* __restrict__ zrow,
    unsigned int* __restrict__ done, float* __restrict__ out)
{
    __shared__ u64t skey[M_TOT];
    __shared__ float soff[40], sscl[40], sbnd[32];
    __shared__ int sTop;
    int t = threadIdx.x;
    int lane = t & 63;
    if (t == 0) sTop = 0;
    if (t < 40) { soff[t] = offsets[t]; sscl[t] = scales[t]; }
    if (t < 32) { sbnd[t] = bounds[t]; }
    if (blockIdx.x == 0 && t < 128) zrow[t] = 0ull;
    if (blockIdx.x == 0 && t < 64)  done[t] = 0u;
    __syncthreads();

    #pragma unroll 4
    for (int s = 0; s < 16; ++s) {
        int u = s * 512 + t;
        int g = u >> 10;
        float raw_s = det[u * 5 + 0];
        float cx    = det[u * 5 + 1];
        float cy    = det[u * 5 + 2];
        float score = __fadd_rn(soff[g * 5 + 0], __fmul_rn(raw_s, sscl[g * 5 + 0]));
        bool valid = (cx < sbnd[g*4+1]) && (cx > sbnd[g*4+0]) &&
                     (cy < sbnd[g*4+3]) && (cy > sbnd[g*4+2]);
        float sv = valid ? score : -1.0f;
        uint32_t dk = desc_key(sv);
        bool push = dk < 0x7FFFFFFFu;
        u64t key = ((u64t)dk << 16) | (unsigned)u;
        u64t bal = __ballot(push);
        if (bal) {
            int lw = 0;
            if (lane == 0) lw = atomicAdd(&sTop, __popcll(bal));
            int wbase = __builtin_amdgcn_readfirstlane(lw);
            if (push) {
                int off = __popcll(bal & ((1ull << lane) - 1ull));
                skey[wbase + off] = key;
            }
        }
    }
    __syncthreads();
    int V = sTop;
    int Vpad = (V + 15) & ~15;
    if (t < Vpad - V) skey[V + t] = ~0ull;
    {
        int zb = blockIdx.x * 320;       // 128 blocks x 320 = 40960
        for (int z = zb + t; z < zb + 320; z += 512) out[z] = 0.0f;
    }
    __syncthreads();
    if (t == 0) *vcnt = (unsigned)V;

    int grp = t >> 3;                    // 0..63
    int jq  = t & 7;
    int i = blockIdx.x * 64 + grp;       // 128*64 = 8192
    int g = i >> 10;
    float raw_s = det[i * 5 + 0];
    float cx    = det[i * 5 + 1];
    float cy    = det[i * 5 + 2];
    float score = __fadd_rn(soff[g * 5 + 0], __fmul_rn(raw_s, sscl[g * 5 + 0]));
    bool valid = (cx < sbnd[g*4+1]) && (cx > sbnd[g*4+0]) &&
                 (cy < sbnd[g*4+3]) && (cy > sbnd[g*4+2]);
    float sv = valid ? score : -1.0f;
    uint32_t dk = desc_key(sv);
    u64t ki = ((u64t)dk << 16) | (unsigned)i;
    const ulonglong2* skey2 = (const ulonglong2*)skey;
    int c = 0;
    int nit = Vpad >> 4;
    #pragma unroll 4
    for (int it = 0; it < nit; ++it) {
        ulonglong2 kj = skey2[it * 8 + jq];
        c += (kj.x < ki) + (kj.y < ki);
    }
    c += __shfl_xor(c, 1);
    c += __shfl_xor(c, 2);
    c += __shfl_xor(c, 4);
    if (jq == 0)
        scatter_one(i, c, ki, det, offsets, scales, boxes_srt, d_srt);
}

// ---- fused mask-build + serial NMS ----
// block 0 (wave 0 only): register-dead consumer; blocks 1..127: builders.
__global__ __launch_bounds__(512) void k34_fused(
    const float4* __restrict__ boxes_srt,
    const u64t* __restrict__ zrow,
    const float* __restrict__ d_srt,
    const unsigned int* __restrict__ vcnt,
    u64t* __restrict__ mask,
    unsigned int* __restrict__ done,
    float* __restrict__ out)
{
    int V = (int)*vcnt;
    int nwords = (V + 63) >> 6;
    int nc = (V + 127) >> 7;             // 128-wide chunks
    int tid = threadIdx.x;

    if (blockIdx.x != 0) {
        // ---------------- builders (r19 chunk-major enumeration) ----------
        __shared__ float4 sb[8 * 65];
        __shared__ float  sa[8 * 65];
        int b = (int)blockIdx.x - 1;     // 0..126
        int gpre = 0;                    // global tile prefix
        for (int c = 0; c < nc; ++c) {
            int w0 = 2 * c;
            int Wc = nwords - w0;                  // >= 1 for c < nc
            int tiles = 2 * ((Wc + 7) >> 3);       // 2 row-halves x word-octets
            int tau0 = ((b - gpre) % 127 + 127) % 127;
            for (int tau = tau0; tau < tiles; tau += 127) {
                int rt = tau & 1, wt = tau >> 1;
                int rowbase = c * 128 + rt * 64;
                int wbase = w0 + wt * 8;
                // stage 8 column groups (512 boxes) coalesced
                {
                    int u = tid;
                    float4 bb = boxes_srt[min(wbase * 64 + u, M_TOT - 1)];
                    int cc = u >> 6, jj = u & 63;
                    sb[cc * 65 + jj] = bb;
                    sa[cc * 65 + jj] = __fmul_rn(fmaxf(__fsub_rn(bb.z, bb.x), 0.0f),
                                                 fmaxf(__fsub_rn(bb.w, bb.y), 0.0f));
                }
                __syncthreads();
                int r  = rowbase + (tid >> 3);
                int wl = tid & 7;
                int w  = wbase + wl;
                if (r < V && w < nwords) {
                    float4 bi = boxes_srt[r];
                    float ai = __fmul_rn(fmaxf(__fsub_rn(bi.z, bi.x), 0.0f),
                                         fmaxf(__fsub_rn(bi.w, bi.y), 0.0f));
                    u64t bits = 0;
                    #pragma unroll 4
                    for (int jj = 0; jj < 64; ++jj) {
                        float4 bj = sb[wl * 65 + jj];
                        float aj = sa[wl * 65 + jj];
                        float iw = fmaxf(__fsub_rn(fminf(bi.z, bj.z), fmaxf(bi.x, bj.x)), 0.0f);
                        float ih = fmaxf(__fsub_rn(fminf(bi.w, bj.w), fmaxf(bi.y, bj.y)), 0.0f);
                        float inter = __fmul_rn(iw, ih);
                        float uni   = __fsub_rn(__fadd_rn(ai, aj), inter);
                        float iou   = __fdiv_rn(inter, fmaxf(uni, 1e-9f));
                        int j = w * 64 + jj;
                        if (j > r && iou > NMS_T) bits |= 1ull << jj;
                    }
                    mask[(size_t)r * 128 + w] = bits;
                }
                __syncthreads();         // all tile writes retired
                if (tid == 0) {
                    int rows_t  = V - rowbase; if (rows_t > 64) rows_t = 64;
                    int words_t = nwords - wbase; if (words_t > 8) words_t = 8;
                    if (rows_t > 0) {
                        __threadfence();             // L2 writeback (agent)
                        __hip_atomic_fetch_add(&done[c], (unsigned)(rows_t * words_t),
                                               __ATOMIC_RELEASE, __HIP_MEMORY_SCOPE_AGENT);
                    }
                }
                __syncthreads();         // protect sb before next stage
            }
            gpre += tiles;
        }
        return;
    }

    // ---------------- block 0: single-wave register-dead consumer --------
    if (tid >= 64) return;               // waves 1..7 idle out
    int lane = tid;
    if (nc <= 0) return;

    u64t dr0 = 0, dr1 = 0;               // lane owns dead words 2*lane, 2*lane+1

    // wait chunk 0 full strip, load its diagonal band
    {
        int rows_c = V; if (rows_c > 128) rows_c = 128;
        unsigned expc = (unsigned)(rows_c * nwords);
        while (__hip_atomic_load(&done[0], __ATOMIC_RELAXED, __HIP_MEMORY_SCOPE_AGENT) < expc)
            __builtin_amdgcn_s_sleep(2);
        (void)__hip_atomic_load(&done[0], __ATOMIC_ACQUIRE, __HIP_MEMORY_SCOPE_AGENT);
    }
    ulonglong2 bl, bh;
    {
        int rl = min(lane,      M_TOT - 1);
        int rh = min(64 + lane, M_TOT - 1);
        bl = *((const ulonglong2*)(mask + (size_t)rl * 128));
        bh = *((const ulonglong2*)(mask + (size_t)rh * 128));
    }
    for (int T = 0; T < nc; ++T) {
        ulonglong2 nbl, nbh;
        bool havenext = (T + 1 < nc);
        if (havenext) {
            int c = T + 1;
            int rows_c = V - c * 128; if (rows_c > 128) rows_c = 128;
            unsigned expc = (unsigned)(rows_c * (nwords - 2 * c));
            while (__hip_atomic_load(&done[c], __ATOMIC_RELAXED, __HIP_MEMORY_SCOPE_AGENT) < expc)
                __builtin_amdgcn_s_sleep(2);
            (void)__hip_atomic_load(&done[c], __ATOMIC_ACQUIRE, __HIP_MEMORY_SCOPE_AGENT);
            int rl = min(c * 128 + lane,      M_TOT - 1);
            int rh = min(c * 128 + 64 + lane, M_TOT - 1);
            int w = min(2 * c, 124);
            nbl = *((const ulonglong2*)(mask + (size_t)rl * 128 + w));
            nbh = *((const ulonglong2*)(mask + (size_t)rh * 128 + w));
        }
        u64t dlo = rdl64(dr0, T);
        u64t dhi = rdl64(dr1, T);
        u64t live_lo = ~dlo;
        u64t live_hi = ~dhi;
        int rem = V - T * 128;
        if (rem < 128) {
            live_lo &= (rem >= 64) ? ~0ull : ((rem <= 0) ? 0ull : ((1ull << rem) - 1ull));
            int rh = rem - 64;
            live_hi &= (rh >= 64) ? ~0ull : ((rh <= 0) ? 0ull : ((1ull << rh) - 1ull));
        }
        u64t km_lo = 0, km_hi = 0;
        while (live_lo) {
            int bs = (int)__builtin_ctzll(live_lo);
            km_lo |= 1ull << bs;
            u64t rml = rdl64(bl.x, bs);
            u64t rmh = rdl64(bl.y, bs);
            live_lo &= ~rml & ~(1ull << bs);
            live_hi &= ~rmh;
        }
        while (live_hi) {
            int bs = (int)__builtin_ctzll(live_hi);
            km_hi |= 1ull << bs;
            u64t rmh = rdl64(bh.y, bs);   // bh.x garbage-safe: live_lo==0
            live_hi &= ~rmh & ~(1ull << bs);
        }
        // kept rows: OR full mask row into per-lane dead regs (covers all
        // future chunks; strip of chunk T is fully built -- gated above),
        // and write the 5 output floats immediately.
        {
            int base = T * 128;
            u64t ka = km_lo, kb = km_hi;
            while (ka | kb) {
                int r0, r1 = -1;
                if (ka) { int b_ = (int)__builtin_ctzll(ka); ka &= ka - 1; r0 = base + b_; }
                else    { int b_ = (int)__builtin_ctzll(kb); kb &= kb - 1; r0 = base + 64 + b_; }
                if (ka)      { int b_ = (int)__builtin_ctzll(ka); ka &= ka - 1; r1 = base + b_; }
                else if (kb) { int b_ = (int)__builtin_ctzll(kb); kb &= kb - 1; r1 = base + 64 + b_; }
                const ulonglong2* p0 = (const ulonglong2*)(mask + (size_t)r0 * 128) + lane;
                const ulonglong2* p1 = (r1 >= 0)
                    ? (const ulonglong2*)(mask + (size_t)r1 * 128) + lane
                    : (const ulonglong2*)zrow + lane;
                ulonglong2 v0 = *p0;
                ulonglong2 v1 = *p1;
                dr0 |= v0.x | v1.x;
                dr1 |= v0.y | v1.y;
                if (lane < 5) {
                    out[r0 * 5 + lane] = d_srt[r0 * 5 + lane];
                    if (r1 >= 0) out[r1 * 5 + lane] = d_srt[r1 * 5 + lane];
                }
            }
        }
        if (havenext) { bl = nbl; bh = nbh; }
    }
}

extern "C" void kernel_launch(void* const* d_in, const int* in_sizes, int n_in,
                              void* d_out, int out_size, void* d_ws, size_t ws_size,
                              hipStream_t stream) {
    const float* det     = (const float*)d_in[0];
    const float* offsets = (const float*)d_in[1];
    const float* scales  = (const float*)d_in[2];
    const float* bounds  = (const float*)d_in[3];
    float* out = (float*)d_out;
    char* ws = (char*)d_ws;
    float4*       boxes = (float4*)(ws + WS_BOX);
    float*        d_srt = (float*)(ws + WS_D);
    unsigned int* vcnt  = (unsigned int*)(ws + WS_VCNT);
    u64t*         zrow  = (u64t*)(ws + WS_ZROW);
    unsigned int* done  = (unsigned int*)(ws + WS_DONE);
    u64t*         mask  = (u64t*)(ws + WS_MASK);

    k2_rank<<<128, 512, 0, stream>>>(det, offsets, scales, bounds, boxes, d_srt,
                                     vcnt, zrow, done, out);
    k34_fused<<<128, 512, 0, stream>>>(boxes, zrow, d_srt, vcnt, mask, done, out);
}